// Round 6
// baseline (211.658 us; speedup 1.0000x reference)
//
#include <hip/hip_runtime.h>

#define BC 16
#define NN 2048
#define FF 128
#define DD 128
#define NEDGES 65536
#define NEG_INF -1e16f
#define LEAK 0.1f
#define CAPR 128   // per-row in-degree cap; P(Poisson(32) > 128) ~ 1e-35

// ---------------- Kernel 1: z = h @ W (+ zero mask & deg) ----------------
__global__ void __launch_bounds__(256) zgemm_kernel(const float* __restrict__ h,
                                                    const float* __restrict__ W,
                                                    float* __restrict__ z,
                                                    unsigned int* __restrict__ mask,
                                                    int* __restrict__ deg) {
    const int tid = threadIdx.x;
    const int gid = blockIdx.x * 256 + tid;
    if (gid < NN * NN / 32) mask[gid] = 0u;   // 1024*256 = 262144 >= 131072
    if (gid < NN) deg[gid] = 0;

    __shared__ float hs[32][FF];   // 16 KB
    const size_t row0 = (size_t)blockIdx.x * 32;
    const float4* hv = (const float4*)(h + row0 * FF);
    float4* hsv = (float4*)&hs[0][0];
#pragma unroll
    for (int i = 0; i < 4; ++i) hsv[tid + 256 * i] = hv[tid + 256 * i];
    __syncthreads();

    const int c0 = (tid & 31) * 4;
    const int r0 = (tid >> 5) * 4;
    float acc[4][4] = {};
    for (int f = 0; f < FF; f += 4) {
        float4 a[4], bb[4];
#pragma unroll
        for (int r = 0; r < 4; ++r) a[r] = *(const float4*)&hs[r0 + r][f];
#pragma unroll
        for (int k = 0; k < 4; ++k) bb[k] = *(const float4*)&W[(f + k) * DD + c0];
#pragma unroll
        for (int r = 0; r < 4; ++r) {
            acc[r][0] += a[r].x * bb[0].x + a[r].y * bb[1].x + a[r].z * bb[2].x + a[r].w * bb[3].x;
            acc[r][1] += a[r].x * bb[0].y + a[r].y * bb[1].y + a[r].z * bb[2].y + a[r].w * bb[3].y;
            acc[r][2] += a[r].x * bb[0].z + a[r].y * bb[1].z + a[r].z * bb[2].z + a[r].w * bb[3].z;
            acc[r][3] += a[r].x * bb[0].w + a[r].y * bb[1].w + a[r].z * bb[2].w + a[r].w * bb[3].w;
        }
    }
#pragma unroll
    for (int r = 0; r < 4; ++r)
        *(float4*)&z[(row0 + r0 + r) * DD + c0] =
            make_float4(acc[r][0], acc[r][1], acc[r][2], acc[r][3]);
}

// ---------------- Kernel 2: edges -> dedup'd CSR in one pass -------------
__global__ void edge_kernel(const int* __restrict__ row, const int* __restrict__ col,
                            unsigned int* __restrict__ mask,
                            unsigned short* __restrict__ hits_g,
                            int* __restrict__ deg) {
    const int e = blockIdx.x * blockDim.x + threadIdx.x;
    if (e < NEDGES) {
        const int r = row[e], c = col[e];
        const unsigned int key = (unsigned int)r * NN + (unsigned int)c;
        const unsigned int bit = 1u << (key & 31u);
        const unsigned int old = atomicOr(&mask[key >> 5], bit);
        if (!(old & bit)) {
            const int slot = atomicAdd(&deg[r], 1);
            if (slot < CAPR) hits_g[r * CAPR + slot] = (unsigned short)c;
        }
    }
}

// ---------------- Kernel 3: two-pass score / softmax / aggregate ---------
// 4 independent waves per block, one wave per (b,n) row. No LDS, no barriers.
// b = ((blk&7)<<1)|(wv&1): round-robin XCD mapping pins batches {2x,2x+1}
// (2 MB of z) in each XCD's 4 MB L2.
// Lane = (eq,hq): eq = edge slot 0..7, hq = dim-slice 0..7 (16 dims/lane).
// Pass 1 computes all chunk scores into sc[16] with NO inter-chunk deps
// (the R5 online-softmax m/l chain serialized 9 bpermutes + 2 exps per
// chunk). One max tree + one sum tree per row, then pass 2 re-gathers v
// (L1/L2-hot) and accumulates with final probabilities — no cross-lane ops.
__global__ void __launch_bounds__(256) gat_kernel(const float* __restrict__ z,
                                                  const unsigned short* __restrict__ hits_g,
                                                  const int* __restrict__ deg,
                                                  float* __restrict__ out) {
    const int tid = threadIdx.x, wv = tid >> 6, ln = tid & 63;
    const int blk = blockIdx.x;
    const int b = ((blk & 7) << 1) | (wv & 1);
    const int n = ((blk >> 3) << 1) | (wv >> 1);
    const int eq = ln >> 3, hq = ln & 7;

    const float* zb = z + ((size_t)b << 18);   // b*2048*128
    const int nh = min(deg[n], CAPR);
    const unsigned short* hrow = hits_g + n * CAPR;

    // this row's z slice (dims hq*16 .. hq*16+15) in registers
    float4 a[4];
    {
        const float4* znp = (const float4*)(zb + ((size_t)n << 7) + (hq << 4));
#pragma unroll
        for (int j = 0; j < 4; ++j) a[j] = znp[j];
    }

    float sc[16];
#pragma unroll
    for (int c = 0; c < 16; ++c) sc[c] = NEG_INF;

    // ---- pass 1: scores only. groups of 4 chunks, wave-uniform gating ----
#pragma unroll
    for (int g = 0; g < 4; ++g) {
        if (g * 32 < nh) {
#pragma unroll
            for (int cc = 0; cc < 4; ++cc) {
                const int c = g * 4 + cc;
                if (c * 8 < nh) {
                    const int e = c * 8 + eq;
                    const int he = hrow[min(e, nh - 1)];
                    const float4* zc = (const float4*)(zb + ((size_t)he << 7) + (hq << 4));
                    float4 v[4];
#pragma unroll
                    for (int j = 0; j < 4; ++j) v[j] = zc[j];
                    float pt = 0.f;
#pragma unroll
                    for (int j = 0; j < 4; ++j)
                        pt += a[j].x * v[j].x + a[j].y * v[j].y +
                              a[j].z * v[j].z + a[j].w * v[j].w;
                    pt += __shfl_xor(pt, 1, 64);
                    pt += __shfl_xor(pt, 2, 64);
                    pt += __shfl_xor(pt, 4, 64);        // full dot in all hq lanes
                    float sv = pt > 0.f ? pt : LEAK * pt;   // leaky_relu(0.1)
                    if (sv == 0.f || e >= nh) sv = NEG_INF; // masked_fill / pad
                    sc[c] = sv;
                }
            }
        }
    }

    // ---- single softmax: row max, then exp + row sum ----
    float mx = sc[0];
#pragma unroll
    for (int c = 1; c < 16; ++c) mx = fmaxf(mx, sc[c]);
#pragma unroll
    for (int off = 8; off <= 32; off <<= 1) mx = fmaxf(mx, __shfl_xor(mx, off, 64));
    const float m = mx;

    float4 acc[4];
#pragma unroll
    for (int j = 0; j < 4; ++j) acc[j] = make_float4(0.f, 0.f, 0.f, 0.f);

    if (nh > 0 && m > 0.5f * NEG_INF) {
        float pr[16];
        float l = 0.f;
#pragma unroll
        for (int g = 0; g < 4; ++g) {
            if (g * 32 < nh) {
#pragma unroll
                for (int cc = 0; cc < 4; ++cc) {
                    const int c = g * 4 + cc;
                    pr[c] = __expf(sc[c] - m);   // pads: exp(-inf)=0
                    l += pr[c];
                }
            } else {
#pragma unroll
                for (int cc = 0; cc < 4; ++cc) pr[g * 4 + cc] = 0.f;
            }
        }
#pragma unroll
        for (int off = 8; off <= 32; off <<= 1) l += __shfl_xor(l, off, 64);

        // ---- pass 2: weighted re-gather, no cross-lane ops in the loop ----
#pragma unroll
        for (int g = 0; g < 4; ++g) {
            if (g * 32 < nh) {
#pragma unroll
                for (int cc = 0; cc < 4; ++cc) {
                    const int c = g * 4 + cc;
                    if (c * 8 < nh) {
                        const int e = c * 8 + eq;
                        const int he = hrow[min(e, nh - 1)];
                        const float4* zc = (const float4*)(zb + ((size_t)he << 7) + (hq << 4));
                        const float p = pr[c];
#pragma unroll
                        for (int j = 0; j < 4; ++j) {
                            float4 v = zc[j];
                            acc[j].x += p * v.x; acc[j].y += p * v.y;
                            acc[j].z += p * v.z; acc[j].w += p * v.w;
                        }
                    }
                }
            }
        }
        // sum acc across the 8 eq-lanes, then normalize
#pragma unroll
        for (int off = 8; off <= 32; off <<= 1) {
#pragma unroll
            for (int j = 0; j < 4; ++j) {
                acc[j].x += __shfl_xor(acc[j].x, off, 64);
                acc[j].y += __shfl_xor(acc[j].y, off, 64);
                acc[j].z += __shfl_xor(acc[j].z, off, 64);
                acc[j].w += __shfl_xor(acc[j].w, off, 64);
            }
        }
        const float inv = 1.f / l;
#pragma unroll
        for (int j = 0; j < 4; ++j) {
            acc[j].x *= inv; acc[j].y *= inv; acc[j].z *= inv; acc[j].w *= inv;
        }
    } else {
        // no valid edge: softmax over uniform -1e16 row -> mean of z[b]
        for (int mm = 0; mm < NN; ++mm) {
            const float4* zr = (const float4*)(zb + ((size_t)mm << 7) + (hq << 4));
#pragma unroll
            for (int j = 0; j < 4; ++j) {
                float4 t = zr[j];
                acc[j].x += t.x; acc[j].y += t.y; acc[j].z += t.z; acc[j].w += t.w;
            }
        }
#pragma unroll
        for (int j = 0; j < 4; ++j) {
            acc[j].x *= (1.f / NN); acc[j].y *= (1.f / NN);
            acc[j].z *= (1.f / NN); acc[j].w *= (1.f / NN);
        }
    }

    // store: lanes with eq<4 write float4 #eq of their hq slice (512 B/row)
    if (eq < 4) {
        float4 o = acc[0];
        if (eq == 1) o = acc[1];
        if (eq == 2) o = acc[2];
        if (eq == 3) o = acc[3];
        *(float4*)(out + (((size_t)b * NN + n) << 7) + (hq << 4) + (eq << 2)) = o;
    }
}

// ---------------- launcher ----------------
extern "C" void kernel_launch(void* const* d_in, const int* in_sizes, int n_in,
                              void* d_out, int out_size, void* d_ws, size_t ws_size,
                              hipStream_t stream) {
    const float* h = (const float*)d_in[0];
    const float* W = (const float*)d_in[1];
    const int* row = (const int*)d_in[2];
    const int* col = (const int*)d_in[3];
    float* out = (float*)d_out;

    char* ws = (char*)d_ws;
    float* z = (float*)ws;                                                     // 16 MB
    unsigned int* mask = (unsigned int*)(ws + (size_t)16 * 1024 * 1024);       // 512 KB
    unsigned short* hits_g = (unsigned short*)(ws + (size_t)16 * 1024 * 1024 + 512 * 1024); // 512 KB
    int* deg = (int*)(ws + (size_t)17 * 1024 * 1024);                          // 8 KB

    zgemm_kernel<<<(BC * NN) / 32, 256, 0, stream>>>(h, W, z, mask, deg);
    edge_kernel<<<NEDGES / 256, 256, 0, stream>>>(row, col, mask, hits_g, deg);
    gat_kernel<<<(BC * NN) / 4, 256, 0, stream>>>(z, hits_g, deg, out);
}

// Round 7
// 189.018 us; speedup vs baseline: 1.1198x; 1.1198x over previous
//
#include <hip/hip_runtime.h>

#define BC 16
#define NN 2048
#define FF 128
#define DD 128
#define NEDGES 65536
#define NEG_INF -1e16f
#define LEAK 0.1f
#define CAPR 128   // per-row in-degree cap; P(Poisson(32) > 128) ~ 1e-35

// ---------------- Kernel 1: z = h @ W (+ zero mask & deg) ----------------
__global__ void __launch_bounds__(256) zgemm_kernel(const float* __restrict__ h,
                                                    const float* __restrict__ W,
                                                    float* __restrict__ z,
                                                    unsigned int* __restrict__ mask,
                                                    int* __restrict__ deg) {
    const int tid = threadIdx.x;
    const int gid = blockIdx.x * 256 + tid;
    if (gid < NN * NN / 32) mask[gid] = 0u;   // 1024*256 = 262144 >= 131072
    if (gid < NN) deg[gid] = 0;

    __shared__ float hs[32][FF];   // 16 KB
    const size_t row0 = (size_t)blockIdx.x * 32;
    const float4* hv = (const float4*)(h + row0 * FF);
    float4* hsv = (float4*)&hs[0][0];
#pragma unroll
    for (int i = 0; i < 4; ++i) hsv[tid + 256 * i] = hv[tid + 256 * i];
    __syncthreads();

    const int c0 = (tid & 31) * 4;
    const int r0 = (tid >> 5) * 4;
    float acc[4][4] = {};
    for (int f = 0; f < FF; f += 4) {
        float4 a[4], bb[4];
#pragma unroll
        for (int r = 0; r < 4; ++r) a[r] = *(const float4*)&hs[r0 + r][f];
#pragma unroll
        for (int k = 0; k < 4; ++k) bb[k] = *(const float4*)&W[(f + k) * DD + c0];
#pragma unroll
        for (int r = 0; r < 4; ++r) {
            acc[r][0] += a[r].x * bb[0].x + a[r].y * bb[1].x + a[r].z * bb[2].x + a[r].w * bb[3].x;
            acc[r][1] += a[r].x * bb[0].y + a[r].y * bb[1].y + a[r].z * bb[2].y + a[r].w * bb[3].y;
            acc[r][2] += a[r].x * bb[0].z + a[r].y * bb[1].z + a[r].z * bb[2].z + a[r].w * bb[3].z;
            acc[r][3] += a[r].x * bb[0].w + a[r].y * bb[1].w + a[r].z * bb[2].w + a[r].w * bb[3].w;
        }
    }
#pragma unroll
    for (int r = 0; r < 4; ++r)
        *(float4*)&z[(row0 + r0 + r) * DD + c0] =
            make_float4(acc[r][0], acc[r][1], acc[r][2], acc[r][3]);
}

// ---------------- Kernel 2: edges -> dedup'd CSR in one pass -------------
__global__ void edge_kernel(const int* __restrict__ row, const int* __restrict__ col,
                            unsigned int* __restrict__ mask,
                            unsigned short* __restrict__ hits_g,
                            int* __restrict__ deg) {
    const int e = blockIdx.x * blockDim.x + threadIdx.x;
    if (e < NEDGES) {
        const int r = row[e], c = col[e];
        const unsigned int key = (unsigned int)r * NN + (unsigned int)c;
        const unsigned int bit = 1u << (key & 31u);
        const unsigned int old = atomicOr(&mask[key >> 5], bit);
        if (!(old & bit)) {
            const int slot = atomicAdd(&deg[r], 1);
            if (slot < CAPR) hits_g[r * CAPR + slot] = (unsigned short)c;
        }
    }
}

// ---------------- Kernel 3: two-pass (max, then exp+aggregate) -----------
// 4 independent waves per block, one wave per (b,n) row. No LDS, no barriers.
// b = ((blk&7)<<1)|(wv&1): round-robin XCD mapping pins batches {2x,2x+1}
// (2 MB of z) in each XCD's 4 MB L2.
// Lane = (eq,hq): eq = edge slot 0..7, hq = dim-slice 0..7 (16 dims/lane).
// Pass 1: row max only (nothing stored). Pass 2: RECOMPUTE dots (gathers are
// L1/L2-hot) and accumulate pr*v. All state is explicit float4 scalars —
// R6's sc[16]/pr[16] arrays were demoted to LDS by promote-alloca
// (LDS_Block_Size=16384 with no __shared__; 2.1e7 bank-conflict cycles).
// Iterations in each pass are fully independent -> loads pipeline.
__global__ void __launch_bounds__(256) gat_kernel(const float* __restrict__ z,
                                                  const unsigned short* __restrict__ hits_g,
                                                  const int* __restrict__ deg,
                                                  float* __restrict__ out) {
    const int tid = threadIdx.x, wv = tid >> 6, ln = tid & 63;
    const int blk = blockIdx.x;
    const int b = ((blk & 7) << 1) | (wv & 1);
    const int n = ((blk >> 3) << 1) | (wv >> 1);
    const int eq = ln >> 3, hq = ln & 7;

    const float* zb = z + ((size_t)b << 18);   // b*2048*128
    const int nh = min(deg[n], CAPR);
    const unsigned short* hrow = hits_g + n * CAPR;

    // this row's z slice (dims hq*16 .. hq*16+15) in registers
    const float4* znp = (const float4*)(zb + ((size_t)n << 7) + (hq << 4));
    const float4 a0 = znp[0], a1 = znp[1], a2 = znp[2], a3 = znp[3];

    // ---- pass 1: row max ----
    float mx = NEG_INF;
    if (nh > 0) {
#pragma unroll 2
        for (int c0 = 0; c0 < nh; c0 += 8) {
            const int e = c0 + eq;
            const int he = hrow[min(e, nh - 1)];
            const float4* zc = (const float4*)(zb + ((size_t)he << 7) + (hq << 4));
            const float4 v0 = zc[0], v1 = zc[1], v2 = zc[2], v3 = zc[3];
            float pt = a0.x * v0.x + a0.y * v0.y + a0.z * v0.z + a0.w * v0.w
                     + a1.x * v1.x + a1.y * v1.y + a1.z * v1.z + a1.w * v1.w
                     + a2.x * v2.x + a2.y * v2.y + a2.z * v2.z + a2.w * v2.w
                     + a3.x * v3.x + a3.y * v3.y + a3.z * v3.z + a3.w * v3.w;
            pt += __shfl_xor(pt, 1, 64);
            pt += __shfl_xor(pt, 2, 64);
            pt += __shfl_xor(pt, 4, 64);                 // full dot in all hq lanes
            float sv = pt > 0.f ? pt : LEAK * pt;        // leaky_relu(0.1)
            if (sv == 0.f || e >= nh) sv = NEG_INF;      // masked_fill / pad
            mx = fmaxf(mx, sv);
        }
    }
#pragma unroll
    for (int off = 8; off <= 32; off <<= 1) mx = fmaxf(mx, __shfl_xor(mx, off, 64));
    const float m = mx;

    float4 acc0 = make_float4(0.f, 0.f, 0.f, 0.f), acc1 = acc0, acc2 = acc0, acc3 = acc0;

    if (nh > 0 && m > 0.5f * NEG_INF) {
        // ---- pass 2: recompute dots, exp with known max, accumulate ----
        float l = 0.f;
#pragma unroll 2
        for (int c0 = 0; c0 < nh; c0 += 8) {
            const int e = c0 + eq;
            const int he = hrow[min(e, nh - 1)];
            const float4* zc = (const float4*)(zb + ((size_t)he << 7) + (hq << 4));
            const float4 v0 = zc[0], v1 = zc[1], v2 = zc[2], v3 = zc[3];
            float pt = a0.x * v0.x + a0.y * v0.y + a0.z * v0.z + a0.w * v0.w
                     + a1.x * v1.x + a1.y * v1.y + a1.z * v1.z + a1.w * v1.w
                     + a2.x * v2.x + a2.y * v2.y + a2.z * v2.z + a2.w * v2.w
                     + a3.x * v3.x + a3.y * v3.y + a3.z * v3.z + a3.w * v3.w;
            pt += __shfl_xor(pt, 1, 64);
            pt += __shfl_xor(pt, 2, 64);
            pt += __shfl_xor(pt, 4, 64);
            float sv = pt > 0.f ? pt : LEAK * pt;
            if (sv == 0.f || e >= nh) sv = NEG_INF;
            const float pr = __expf(sv - m);             // pads/zeros -> 0
            l += pr;
            acc0.x += pr * v0.x; acc0.y += pr * v0.y; acc0.z += pr * v0.z; acc0.w += pr * v0.w;
            acc1.x += pr * v1.x; acc1.y += pr * v1.y; acc1.z += pr * v1.z; acc1.w += pr * v1.w;
            acc2.x += pr * v2.x; acc2.y += pr * v2.y; acc2.z += pr * v2.z; acc2.w += pr * v2.w;
            acc3.x += pr * v3.x; acc3.y += pr * v3.y; acc3.z += pr * v3.z; acc3.w += pr * v3.w;
        }
        // reduce l and acc across the 8 eq-lanes (xor bits 3..5)
#pragma unroll
        for (int off = 8; off <= 32; off <<= 1) {
            l += __shfl_xor(l, off, 64);
            acc0.x += __shfl_xor(acc0.x, off, 64); acc0.y += __shfl_xor(acc0.y, off, 64);
            acc0.z += __shfl_xor(acc0.z, off, 64); acc0.w += __shfl_xor(acc0.w, off, 64);
            acc1.x += __shfl_xor(acc1.x, off, 64); acc1.y += __shfl_xor(acc1.y, off, 64);
            acc1.z += __shfl_xor(acc1.z, off, 64); acc1.w += __shfl_xor(acc1.w, off, 64);
            acc2.x += __shfl_xor(acc2.x, off, 64); acc2.y += __shfl_xor(acc2.y, off, 64);
            acc2.z += __shfl_xor(acc2.z, off, 64); acc2.w += __shfl_xor(acc2.w, off, 64);
            acc3.x += __shfl_xor(acc3.x, off, 64); acc3.y += __shfl_xor(acc3.y, off, 64);
            acc3.z += __shfl_xor(acc3.z, off, 64); acc3.w += __shfl_xor(acc3.w, off, 64);
        }
        const float inv = 1.f / l;
        acc0.x *= inv; acc0.y *= inv; acc0.z *= inv; acc0.w *= inv;
        acc1.x *= inv; acc1.y *= inv; acc1.z *= inv; acc1.w *= inv;
        acc2.x *= inv; acc2.y *= inv; acc2.z *= inv; acc2.w *= inv;
        acc3.x *= inv; acc3.y *= inv; acc3.z *= inv; acc3.w *= inv;
    } else {
        // no valid edge: softmax over uniform -1e16 row -> mean of z[b]
        for (int mm = 0; mm < NN; ++mm) {
            const float4* zr = (const float4*)(zb + ((size_t)mm << 7) + (hq << 4));
            const float4 t0 = zr[0], t1 = zr[1], t2 = zr[2], t3 = zr[3];
            acc0.x += t0.x; acc0.y += t0.y; acc0.z += t0.z; acc0.w += t0.w;
            acc1.x += t1.x; acc1.y += t1.y; acc1.z += t1.z; acc1.w += t1.w;
            acc2.x += t2.x; acc2.y += t2.y; acc2.z += t2.z; acc2.w += t2.w;
            acc3.x += t3.x; acc3.y += t3.y; acc3.z += t3.z; acc3.w += t3.w;
        }
        const float s = 1.f / NN;
        acc0.x *= s; acc0.y *= s; acc0.z *= s; acc0.w *= s;
        acc1.x *= s; acc1.y *= s; acc1.z *= s; acc1.w *= s;
        acc2.x *= s; acc2.y *= s; acc2.z *= s; acc2.w *= s;
        acc3.x *= s; acc3.y *= s; acc3.z *= s; acc3.w *= s;
    }

    // store: lanes with eq<4 write float4 #eq of their hq slice (512 B/row)
    if (eq < 4) {
        float4 o = acc0;
        if (eq == 1) o = acc1;
        if (eq == 2) o = acc2;
        if (eq == 3) o = acc3;
        *(float4*)(out + (((size_t)b * NN + n) << 7) + (hq << 4) + (eq << 2)) = o;
    }
}

// ---------------- launcher ----------------
extern "C" void kernel_launch(void* const* d_in, const int* in_sizes, int n_in,
                              void* d_out, int out_size, void* d_ws, size_t ws_size,
                              hipStream_t stream) {
    const float* h = (const float*)d_in[0];
    const float* W = (const float*)d_in[1];
    const int* row = (const int*)d_in[2];
    const int* col = (const int*)d_in[3];
    float* out = (float*)d_out;

    char* ws = (char*)d_ws;
    float* z = (float*)ws;                                                     // 16 MB
    unsigned int* mask = (unsigned int*)(ws + (size_t)16 * 1024 * 1024);       // 512 KB
    unsigned short* hits_g = (unsigned short*)(ws + (size_t)16 * 1024 * 1024 + 512 * 1024); // 512 KB
    int* deg = (int*)(ws + (size_t)17 * 1024 * 1024);                          // 8 KB

    zgemm_kernel<<<(BC * NN) / 32, 256, 0, stream>>>(h, W, z, mask, deg);
    edge_kernel<<<NEDGES / 256, 256, 0, stream>>>(row, col, mask, hits_g, deg);
    gat_kernel<<<(BC * NN) / 4, 256, 0, stream>>>(z, hits_g, deg, out);
}

// Round 8
// 159.555 us; speedup vs baseline: 1.3265x; 1.1847x over previous
//
#include <hip/hip_runtime.h>

#define BC 16
#define NN 2048
#define FF 128
#define DD 128
#define NEDGES 65536
#define NEG_INF -1e16f
#define LEAK 0.1f
#define CAPR 128   // per-row in-degree cap; P(Poisson(32) > 128) ~ 1e-35

// ---------------- Kernel 1: z = h @ W (+ zero mask & deg) ----------------
__global__ void __launch_bounds__(256) zgemm_kernel(const float* __restrict__ h,
                                                    const float* __restrict__ W,
                                                    float* __restrict__ z,
                                                    unsigned int* __restrict__ mask,
                                                    int* __restrict__ deg) {
    const int tid = threadIdx.x;
    const int gid = blockIdx.x * 256 + tid;
    if (gid < NN * NN / 32) mask[gid] = 0u;   // 1024*256 = 262144 >= 131072
    if (gid < NN) deg[gid] = 0;

    __shared__ float hs[32][FF];   // 16 KB
    const size_t row0 = (size_t)blockIdx.x * 32;
    const float4* hv = (const float4*)(h + row0 * FF);
    float4* hsv = (float4*)&hs[0][0];
#pragma unroll
    for (int i = 0; i < 4; ++i) hsv[tid + 256 * i] = hv[tid + 256 * i];
    __syncthreads();

    const int c0 = (tid & 31) * 4;
    const int r0 = (tid >> 5) * 4;
    float acc[4][4] = {};
    for (int f = 0; f < FF; f += 4) {
        float4 a[4], bb[4];
#pragma unroll
        for (int r = 0; r < 4; ++r) a[r] = *(const float4*)&hs[r0 + r][f];
#pragma unroll
        for (int k = 0; k < 4; ++k) bb[k] = *(const float4*)&W[(f + k) * DD + c0];
#pragma unroll
        for (int r = 0; r < 4; ++r) {
            acc[r][0] += a[r].x * bb[0].x + a[r].y * bb[1].x + a[r].z * bb[2].x + a[r].w * bb[3].x;
            acc[r][1] += a[r].x * bb[0].y + a[r].y * bb[1].y + a[r].z * bb[2].y + a[r].w * bb[3].y;
            acc[r][2] += a[r].x * bb[0].z + a[r].y * bb[1].z + a[r].z * bb[2].z + a[r].w * bb[3].z;
            acc[r][3] += a[r].x * bb[0].w + a[r].y * bb[1].w + a[r].z * bb[2].w + a[r].w * bb[3].w;
        }
    }
#pragma unroll
    for (int r = 0; r < 4; ++r)
        *(float4*)&z[(row0 + r0 + r) * DD + c0] =
            make_float4(acc[r][0], acc[r][1], acc[r][2], acc[r][3]);
}

// ---------------- Kernel 2: edges -> dedup'd CSR in one pass -------------
__global__ void edge_kernel(const int* __restrict__ row, const int* __restrict__ col,
                            unsigned int* __restrict__ mask,
                            unsigned short* __restrict__ hits_g,
                            int* __restrict__ deg) {
    const int e = blockIdx.x * blockDim.x + threadIdx.x;
    if (e < NEDGES) {
        const int r = row[e], c = col[e];
        const unsigned int key = (unsigned int)r * NN + (unsigned int)c;
        const unsigned int bit = 1u << (key & 31u);
        const unsigned int old = atomicOr(&mask[key >> 5], bit);
        if (!(old & bit)) {
            const int slot = atomicAdd(&deg[r], 1);
            if (slot < CAPR) hits_g[r * CAPR + slot] = (unsigned short)c;
        }
    }
}

// ---------------- Kernel 3: single-pass, lane-local online softmax -------
// 4 independent waves per block, one wave per (b,n) row. No LDS, no barriers.
// b = ((blk&7)<<1)|(wv&1): round-robin XCD mapping pins batches {2x,2x+1}
// (2 MB of z) in each XCD's 4 MB L2.
// Lane = (eq,hq): eq = edge slot 0..7, hq = dim-slice 0..7 (16 dims/lane).
// Each eq-group runs ONLINE softmax over its own edge subset with lane-local
// (m,l) — the only cross-lane ops in the loop are the 3 dot shuffles, which
// carry no loop dependence and pipeline ahead (R5 had the max/sum wave
// reductions inside the carried chain: 9 serialized bpermutes per chunk;
// R7's two-pass fix doubled gather traffic instead). One cross-eq merge at
// the end: global M, rescale by exp(m-M) (lanes that saw only pads have
// m=-1e16 -> alpha=0, their garbage l/acc self-cancels), then sum.
// All state is explicit scalars — no arrays for promote-alloca to demote.
__global__ void __launch_bounds__(256) gat_kernel(const float* __restrict__ z,
                                                  const unsigned short* __restrict__ hits_g,
                                                  const int* __restrict__ deg,
                                                  float* __restrict__ out) {
    const int tid = threadIdx.x, wv = tid >> 6, ln = tid & 63;
    const int blk = blockIdx.x;
    const int b = ((blk & 7) << 1) | (wv & 1);
    const int n = ((blk >> 3) << 1) | (wv >> 1);
    const int eq = ln >> 3, hq = ln & 7;

    const float* zb = z + ((size_t)b << 18);   // b*2048*128
    const int nh = min(deg[n], CAPR);
    const unsigned short* hrow = hits_g + n * CAPR;

    // this row's z slice (dims hq*16 .. hq*16+15) in registers
    const float4* znp = (const float4*)(zb + ((size_t)n << 7) + (hq << 4));
    const float4 a0 = znp[0], a1 = znp[1], a2 = znp[2], a3 = znp[3];

    float m = NEG_INF, l = 0.f;
    float4 acc0 = make_float4(0.f, 0.f, 0.f, 0.f), acc1 = acc0, acc2 = acc0, acc3 = acc0;

#pragma unroll 2
    for (int c0 = 0; c0 < nh; c0 += 8) {
        const int e = c0 + eq;
        const int he = hrow[min(e, nh - 1)];     // pad lanes re-read a real edge
        const float4* zc = (const float4*)(zb + ((size_t)he << 7) + (hq << 4));
        const float4 v0 = zc[0], v1 = zc[1], v2 = zc[2], v3 = zc[3];
        float pt = a0.x * v0.x + a0.y * v0.y + a0.z * v0.z + a0.w * v0.w
                 + a1.x * v1.x + a1.y * v1.y + a1.z * v1.z + a1.w * v1.w
                 + a2.x * v2.x + a2.y * v2.y + a2.z * v2.z + a2.w * v2.w
                 + a3.x * v3.x + a3.y * v3.y + a3.z * v3.z + a3.w * v3.w;
        pt += __shfl_xor(pt, 1, 64);
        pt += __shfl_xor(pt, 2, 64);
        pt += __shfl_xor(pt, 4, 64);             // full 128-dim dot in all hq lanes
        float sv = pt > 0.f ? pt : LEAK * pt;    // leaky_relu(0.1)
        if (sv == 0.f || e >= nh) sv = NEG_INF;  // masked_fill(att==0) / pad

        // lane-local online update (carried chain: fmax + 2 exp + fma)
        const float mnew = fmaxf(m, sv);
        const float alpha = __expf(m - mnew);    // 1 while m==mnew==NEG_INF
        const float pr = __expf(sv - mnew);
        l = l * alpha + pr;
        acc0.x = acc0.x * alpha + pr * v0.x; acc0.y = acc0.y * alpha + pr * v0.y;
        acc0.z = acc0.z * alpha + pr * v0.z; acc0.w = acc0.w * alpha + pr * v0.w;
        acc1.x = acc1.x * alpha + pr * v1.x; acc1.y = acc1.y * alpha + pr * v1.y;
        acc1.z = acc1.z * alpha + pr * v1.z; acc1.w = acc1.w * alpha + pr * v1.w;
        acc2.x = acc2.x * alpha + pr * v2.x; acc2.y = acc2.y * alpha + pr * v2.y;
        acc2.z = acc2.z * alpha + pr * v2.z; acc2.w = acc2.w * alpha + pr * v2.w;
        acc3.x = acc3.x * alpha + pr * v3.x; acc3.y = acc3.y * alpha + pr * v3.y;
        acc3.z = acc3.z * alpha + pr * v3.z; acc3.w = acc3.w * alpha + pr * v3.w;
        m = mnew;
    }

    // ---- cross-eq merge: global row max, rescale, sum ----
    float M = m;
#pragma unroll
    for (int off = 8; off <= 32; off <<= 1) M = fmaxf(M, __shfl_xor(M, off, 64));

    if (nh > 0 && M > 0.5f * NEG_INF) {
        const float al = __expf(m - M);          // 0 for all-pad lanes
        l *= al;
        acc0.x *= al; acc0.y *= al; acc0.z *= al; acc0.w *= al;
        acc1.x *= al; acc1.y *= al; acc1.z *= al; acc1.w *= al;
        acc2.x *= al; acc2.y *= al; acc2.z *= al; acc2.w *= al;
        acc3.x *= al; acc3.y *= al; acc3.z *= al; acc3.w *= al;
#pragma unroll
        for (int off = 8; off <= 32; off <<= 1) {
            l += __shfl_xor(l, off, 64);
            acc0.x += __shfl_xor(acc0.x, off, 64); acc0.y += __shfl_xor(acc0.y, off, 64);
            acc0.z += __shfl_xor(acc0.z, off, 64); acc0.w += __shfl_xor(acc0.w, off, 64);
            acc1.x += __shfl_xor(acc1.x, off, 64); acc1.y += __shfl_xor(acc1.y, off, 64);
            acc1.z += __shfl_xor(acc1.z, off, 64); acc1.w += __shfl_xor(acc1.w, off, 64);
            acc2.x += __shfl_xor(acc2.x, off, 64); acc2.y += __shfl_xor(acc2.y, off, 64);
            acc2.z += __shfl_xor(acc2.z, off, 64); acc2.w += __shfl_xor(acc2.w, off, 64);
            acc3.x += __shfl_xor(acc3.x, off, 64); acc3.y += __shfl_xor(acc3.y, off, 64);
            acc3.z += __shfl_xor(acc3.z, off, 64); acc3.w += __shfl_xor(acc3.w, off, 64);
        }
        const float inv = 1.f / l;
        acc0.x *= inv; acc0.y *= inv; acc0.z *= inv; acc0.w *= inv;
        acc1.x *= inv; acc1.y *= inv; acc1.z *= inv; acc1.w *= inv;
        acc2.x *= inv; acc2.y *= inv; acc2.z *= inv; acc2.w *= inv;
        acc3.x *= inv; acc3.y *= inv; acc3.z *= inv; acc3.w *= inv;
    } else {
        // no valid edge: softmax over uniform -1e16 row -> mean of z[b]
        acc0 = make_float4(0.f, 0.f, 0.f, 0.f); acc1 = acc0; acc2 = acc0; acc3 = acc0;
        for (int mm = 0; mm < NN; ++mm) {
            const float4* zr = (const float4*)(zb + ((size_t)mm << 7) + (hq << 4));
            const float4 t0 = zr[0], t1 = zr[1], t2 = zr[2], t3 = zr[3];
            acc0.x += t0.x; acc0.y += t0.y; acc0.z += t0.z; acc0.w += t0.w;
            acc1.x += t1.x; acc1.y += t1.y; acc1.z += t1.z; acc1.w += t1.w;
            acc2.x += t2.x; acc2.y += t2.y; acc2.z += t2.z; acc2.w += t2.w;
            acc3.x += t3.x; acc3.y += t3.y; acc3.z += t3.z; acc3.w += t3.w;
        }
        const float s = 1.f / NN;
        acc0.x *= s; acc0.y *= s; acc0.z *= s; acc0.w *= s;
        acc1.x *= s; acc1.y *= s; acc1.z *= s; acc1.w *= s;
        acc2.x *= s; acc2.y *= s; acc2.z *= s; acc2.w *= s;
        acc3.x *= s; acc3.y *= s; acc3.z *= s; acc3.w *= s;
    }

    // store: lanes with eq<4 write float4 #eq of their hq slice (512 B/row)
    if (eq < 4) {
        float4 o = acc0;
        if (eq == 1) o = acc1;
        if (eq == 2) o = acc2;
        if (eq == 3) o = acc3;
        *(float4*)(out + (((size_t)b * NN + n) << 7) + (hq << 4) + (eq << 2)) = o;
    }
}

// ---------------- launcher ----------------
extern "C" void kernel_launch(void* const* d_in, const int* in_sizes, int n_in,
                              void* d_out, int out_size, void* d_ws, size_t ws_size,
                              hipStream_t stream) {
    const float* h = (const float*)d_in[0];
    const float* W = (const float*)d_in[1];
    const int* row = (const int*)d_in[2];
    const int* col = (const int*)d_in[3];
    float* out = (float*)d_out;

    char* ws = (char*)d_ws;
    float* z = (float*)ws;                                                     // 16 MB
    unsigned int* mask = (unsigned int*)(ws + (size_t)16 * 1024 * 1024);       // 512 KB
    unsigned short* hits_g = (unsigned short*)(ws + (size_t)16 * 1024 * 1024 + 512 * 1024); // 512 KB
    int* deg = (int*)(ws + (size_t)17 * 1024 * 1024);                          // 8 KB

    zgemm_kernel<<<(BC * NN) / 32, 256, 0, stream>>>(h, W, z, mask, deg);
    edge_kernel<<<NEDGES / 256, 256, 0, stream>>>(row, col, mask, hits_g, deg);
    gat_kernel<<<(BC * NN) / 4, 256, 0, stream>>>(z, hits_g, deg, out);
}

// Round 9
// 149.590 us; speedup vs baseline: 1.4149x; 1.0666x over previous
//
#include <hip/hip_runtime.h>

#define BC 16
#define NN 2048
#define FF 128
#define DD 128
#define NEDGES 65536
#define NEG_INF -1e16f
#define LEAK 0.1f
#define CAPR 128   // per-row in-degree cap; P(Poisson(32) > 128) ~ 1e-35

// ---------------- Kernel 1 (fused): edge atomicOr + z = h @ W ------------
// blocks 0..255: set adjacency bits (mask pre-zeroed by hipMemsetAsync).
// blocks 256..1279: register-tiled zgemm, one [32 x 128] tile of z each.
// Pure-OR edge path: R8's slot-reserving atomicAdd(&deg[r]) serialized ~32
// same-address device-scope atomics per row (~20-30 us); CSR slots now come
// from a shuffle prefix-scan in csr_kernel instead (zero atomics).
__global__ void __launch_bounds__(256) zedge_kernel(const float* __restrict__ h,
                                                    const float* __restrict__ W,
                                                    float* __restrict__ z,
                                                    const int* __restrict__ row,
                                                    const int* __restrict__ col,
                                                    unsigned int* __restrict__ mask) {
    const int tid = threadIdx.x;
    const int blk = blockIdx.x;

    if (blk < 256) {   // ---- edge part: runs first, overlaps zgemm fill
        const int e = blk * 256 + tid;
        const unsigned int key = (unsigned int)row[e] * NN + (unsigned int)col[e];
        atomicOr(&mask[key >> 5], 1u << (key & 31u));
        return;
    }

    // ---- zgemm part
    __shared__ float hs[32][FF];   // 16 KB
    const size_t row0 = (size_t)(blk - 256) * 32;
    const float4* hv = (const float4*)(h + row0 * FF);
    float4* hsv = (float4*)&hs[0][0];
#pragma unroll
    for (int i = 0; i < 4; ++i) hsv[tid + 256 * i] = hv[tid + 256 * i];
    __syncthreads();

    const int c0 = (tid & 31) * 4;
    const int r0 = (tid >> 5) * 4;
    float acc[4][4] = {};
    for (int f = 0; f < FF; f += 4) {
        float4 a[4], bb[4];
#pragma unroll
        for (int r = 0; r < 4; ++r) a[r] = *(const float4*)&hs[r0 + r][f];
#pragma unroll
        for (int k = 0; k < 4; ++k) bb[k] = *(const float4*)&W[(f + k) * DD + c0];
#pragma unroll
        for (int r = 0; r < 4; ++r) {
            acc[r][0] += a[r].x * bb[0].x + a[r].y * bb[1].x + a[r].z * bb[2].x + a[r].w * bb[3].x;
            acc[r][1] += a[r].x * bb[0].y + a[r].y * bb[1].y + a[r].z * bb[2].y + a[r].w * bb[3].y;
            acc[r][2] += a[r].x * bb[0].z + a[r].y * bb[1].z + a[r].z * bb[2].z + a[r].w * bb[3].z;
            acc[r][3] += a[r].x * bb[0].w + a[r].y * bb[1].w + a[r].z * bb[2].w + a[r].w * bb[3].w;
        }
    }
#pragma unroll
    for (int r = 0; r < 4; ++r)
        *(float4*)&z[(row0 + r0 + r) * DD + c0] =
            make_float4(acc[r][0], acc[r][1], acc[r][2], acc[r][3]);
}

// ---------------- Kernel 2: bitmask -> sorted CSR, zero atomics ----------
// one wave per row. Lane ln owns mask word ln (64 words = 2048 cols).
// Exclusive shuffle prefix-scan of popcounts gives each lane its slot base;
// bits decode in ascending column order -> gat gathers walk z[b] forward.
__global__ void __launch_bounds__(256) csr_kernel(const unsigned int* __restrict__ mask,
                                                  unsigned short* __restrict__ hits_g,
                                                  int* __restrict__ deg) {
    const int tid = threadIdx.x, wv = tid >> 6, ln = tid & 63;
    const int n = blockIdx.x * 4 + wv;
    unsigned int bits = mask[n * 64 + ln];
    const int cnt = __popc(bits);
    int pre = cnt;
#pragma unroll
    for (int off = 1; off <= 32; off <<= 1) {
        const int t = __shfl_up(pre, off, 64);
        if (ln >= off) pre += t;
    }
    if (ln == 63) deg[n] = pre;        // inclusive total (gat clamps at CAPR)
    int slot = pre - cnt;              // exclusive prefix = this lane's base
    while (bits) {
        const int bit = __ffs(bits) - 1;
        bits &= bits - 1;
        if (slot < CAPR) hits_g[n * CAPR + slot] = (unsigned short)(ln * 32 + bit);
        ++slot;
    }
}

// ---------------- Kernel 3: single-pass, lane-local online softmax -------
// (unchanged from R8: 57.6 us, VALU-bound, zero LDS/barriers/conflicts)
__global__ void __launch_bounds__(256) gat_kernel(const float* __restrict__ z,
                                                  const unsigned short* __restrict__ hits_g,
                                                  const int* __restrict__ deg,
                                                  float* __restrict__ out) {
    const int tid = threadIdx.x, wv = tid >> 6, ln = tid & 63;
    const int blk = blockIdx.x;
    const int b = ((blk & 7) << 1) | (wv & 1);
    const int n = ((blk >> 3) << 1) | (wv >> 1);
    const int eq = ln >> 3, hq = ln & 7;

    const float* zb = z + ((size_t)b << 18);   // b*2048*128
    const int nh = min(deg[n], CAPR);
    const unsigned short* hrow = hits_g + n * CAPR;

    const float4* znp = (const float4*)(zb + ((size_t)n << 7) + (hq << 4));
    const float4 a0 = znp[0], a1 = znp[1], a2 = znp[2], a3 = znp[3];

    float m = NEG_INF, l = 0.f;
    float4 acc0 = make_float4(0.f, 0.f, 0.f, 0.f), acc1 = acc0, acc2 = acc0, acc3 = acc0;

#pragma unroll 2
    for (int c0 = 0; c0 < nh; c0 += 8) {
        const int e = c0 + eq;
        const int he = hrow[min(e, nh - 1)];     // pad lanes re-read a real edge
        const float4* zc = (const float4*)(zb + ((size_t)he << 7) + (hq << 4));
        const float4 v0 = zc[0], v1 = zc[1], v2 = zc[2], v3 = zc[3];
        float pt = a0.x * v0.x + a0.y * v0.y + a0.z * v0.z + a0.w * v0.w
                 + a1.x * v1.x + a1.y * v1.y + a1.z * v1.z + a1.w * v1.w
                 + a2.x * v2.x + a2.y * v2.y + a2.z * v2.z + a2.w * v2.w
                 + a3.x * v3.x + a3.y * v3.y + a3.z * v3.z + a3.w * v3.w;
        pt += __shfl_xor(pt, 1, 64);
        pt += __shfl_xor(pt, 2, 64);
        pt += __shfl_xor(pt, 4, 64);             // full 128-dim dot in all hq lanes
        float sv = pt > 0.f ? pt : LEAK * pt;    // leaky_relu(0.1)
        if (sv == 0.f || e >= nh) sv = NEG_INF;  // masked_fill(att==0) / pad

        const float mnew = fmaxf(m, sv);
        const float alpha = __expf(m - mnew);    // 1 while m==mnew==NEG_INF
        const float pr = __expf(sv - mnew);
        l = l * alpha + pr;
        acc0.x = acc0.x * alpha + pr * v0.x; acc0.y = acc0.y * alpha + pr * v0.y;
        acc0.z = acc0.z * alpha + pr * v0.z; acc0.w = acc0.w * alpha + pr * v0.w;
        acc1.x = acc1.x * alpha + pr * v1.x; acc1.y = acc1.y * alpha + pr * v1.y;
        acc1.z = acc1.z * alpha + pr * v1.z; acc1.w = acc1.w * alpha + pr * v1.w;
        acc2.x = acc2.x * alpha + pr * v2.x; acc2.y = acc2.y * alpha + pr * v2.y;
        acc2.z = acc2.z * alpha + pr * v2.z; acc2.w = acc2.w * alpha + pr * v2.w;
        acc3.x = acc3.x * alpha + pr * v3.x; acc3.y = acc3.y * alpha + pr * v3.y;
        acc3.z = acc3.z * alpha + pr * v3.z; acc3.w = acc3.w * alpha + pr * v3.w;
        m = mnew;
    }

    float M = m;
#pragma unroll
    for (int off = 8; off <= 32; off <<= 1) M = fmaxf(M, __shfl_xor(M, off, 64));

    if (nh > 0 && M > 0.5f * NEG_INF) {
        const float al = __expf(m - M);          // 0 for all-pad lanes
        l *= al;
        acc0.x *= al; acc0.y *= al; acc0.z *= al; acc0.w *= al;
        acc1.x *= al; acc1.y *= al; acc1.z *= al; acc1.w *= al;
        acc2.x *= al; acc2.y *= al; acc2.z *= al; acc2.w *= al;
        acc3.x *= al; acc3.y *= al; acc3.z *= al; acc3.w *= al;
#pragma unroll
        for (int off = 8; off <= 32; off <<= 1) {
            l += __shfl_xor(l, off, 64);
            acc0.x += __shfl_xor(acc0.x, off, 64); acc0.y += __shfl_xor(acc0.y, off, 64);
            acc0.z += __shfl_xor(acc0.z, off, 64); acc0.w += __shfl_xor(acc0.w, off, 64);
            acc1.x += __shfl_xor(acc1.x, off, 64); acc1.y += __shfl_xor(acc1.y, off, 64);
            acc1.z += __shfl_xor(acc1.z, off, 64); acc1.w += __shfl_xor(acc1.w, off, 64);
            acc2.x += __shfl_xor(acc2.x, off, 64); acc2.y += __shfl_xor(acc2.y, off, 64);
            acc2.z += __shfl_xor(acc2.z, off, 64); acc2.w += __shfl_xor(acc2.w, off, 64);
            acc3.x += __shfl_xor(acc3.x, off, 64); acc3.y += __shfl_xor(acc3.y, off, 64);
            acc3.z += __shfl_xor(acc3.z, off, 64); acc3.w += __shfl_xor(acc3.w, off, 64);
        }
        const float inv = 1.f / l;
        acc0.x *= inv; acc0.y *= inv; acc0.z *= inv; acc0.w *= inv;
        acc1.x *= inv; acc1.y *= inv; acc1.z *= inv; acc1.w *= inv;
        acc2.x *= inv; acc2.y *= inv; acc2.z *= inv; acc2.w *= inv;
        acc3.x *= inv; acc3.y *= inv; acc3.z *= inv; acc3.w *= inv;
    } else {
        // no valid edge: softmax over uniform -1e16 row -> mean of z[b]
        acc0 = make_float4(0.f, 0.f, 0.f, 0.f); acc1 = acc0; acc2 = acc0; acc3 = acc0;
        for (int mm = 0; mm < NN; ++mm) {
            const float4* zr = (const float4*)(zb + ((size_t)mm << 7) + (hq << 4));
            const float4 t0 = zr[0], t1 = zr[1], t2 = zr[2], t3 = zr[3];
            acc0.x += t0.x; acc0.y += t0.y; acc0.z += t0.z; acc0.w += t0.w;
            acc1.x += t1.x; acc1.y += t1.y; acc1.z += t1.z; acc1.w += t1.w;
            acc2.x += t2.x; acc2.y += t2.y; acc2.z += t2.z; acc2.w += t2.w;
            acc3.x += t3.x; acc3.y += t3.y; acc3.z += t3.z; acc3.w += t3.w;
        }
        const float s = 1.f / NN;
        acc0.x *= s; acc0.y *= s; acc0.z *= s; acc0.w *= s;
        acc1.x *= s; acc1.y *= s; acc1.z *= s; acc1.w *= s;
        acc2.x *= s; acc2.y *= s; acc2.z *= s; acc2.w *= s;
        acc3.x *= s; acc3.y *= s; acc3.z *= s; acc3.w *= s;
    }

    if (eq < 4) {
        float4 o = acc0;
        if (eq == 1) o = acc1;
        if (eq == 2) o = acc2;
        if (eq == 3) o = acc3;
        *(float4*)(out + (((size_t)b * NN + n) << 7) + (hq << 4) + (eq << 2)) = o;
    }
}

// ---------------- launcher ----------------
extern "C" void kernel_launch(void* const* d_in, const int* in_sizes, int n_in,
                              void* d_out, int out_size, void* d_ws, size_t ws_size,
                              hipStream_t stream) {
    const float* h = (const float*)d_in[0];
    const float* W = (const float*)d_in[1];
    const int* row = (const int*)d_in[2];
    const int* col = (const int*)d_in[3];
    float* out = (float*)d_out;

    char* ws = (char*)d_ws;
    float* z = (float*)ws;                                                     // 16 MB
    unsigned int* mask = (unsigned int*)(ws + (size_t)16 * 1024 * 1024);       // 512 KB
    unsigned short* hits_g = (unsigned short*)(ws + (size_t)16 * 1024 * 1024 + 512 * 1024); // 512 KB
    int* deg = (int*)(ws + (size_t)17 * 1024 * 1024);                          // 8 KB

    hipMemsetAsync(mask, 0, (size_t)NN * NN / 8, stream);   // DMA, ~2 us
    zedge_kernel<<<1280, 256, 0, stream>>>(h, W, z, row, col, mask);
    csr_kernel<<<NN / 4, 256, 0, stream>>>(mask, hits_g, deg);
    gat_kernel<<<(BC * NN) / 4, 256, 0, stream>>>(z, hits_g, deg, out);
}